// Round 1
// baseline (3142.601 us; speedup 1.0000x reference)
//
#include <hip/hip_runtime.h>
#include <math.h>

#define NB 128
#define NC 320
#define NPIX 256
#define NG 5
#define CPG 64      // channels per group
#define NHID 40     // C / RATIO

__device__ __forceinline__ float sigf(float x){ return 1.0f/(1.0f+expf(-x)); }

// ---------------------------------------------------------------------------
// k_prep: build the 3 circular-convolution kernels (16x16 each) implied by the
// frequency masks. kern[band][d1*16+d2] = (1/256) sum_s m[s] cos(2pi((s1+8)d1+(s2+8)d2)/16)
// Replicates JAX fp32 linspace / dist / sigmoid arithmetic.
// ---------------------------------------------------------------------------
__global__ __launch_bounds__(256) void k_prep(const float* __restrict__ lowc,
                                              const float* __restrict__ highc,
                                              float* __restrict__ kern){
  int t = threadIdx.x;
  int d1 = t >> 4, d2 = t & 15;
  float lc = lowc[0], hc = highc[0];
  float s0 = 0.f, s1 = 0.f, s2 = 0.f;
  const float step = 2.0f / 15.0f;
  for (int a1 = 0; a1 < 16; ++a1){
    float cy = -1.0f + step * (float)a1;
    for (int a2 = 0; a2 < 16; ++a2){
      float cx = -1.0f + step * (float)a2;
      float dist = sqrtf(cx*cx + cy*cy) / 1.41421356237309515f;
      float lm = sigf((lc - dist) / 1e-6f);
      float hm = sigf((dist - hc) / 1e-6f);
      float mm = sigf((dist - lc) / 1e-6f) * sigf((hc - dist) / 1e-6f);
      int ang = ((a1 + 8) * d1 + (a2 + 8) * d2) & 15;
      float cv = cosf((float)ang * 0.392699081698724154f);  // 2*pi/16
      s0 += lm * cv; s1 += mm * cv; s2 += hm * cv;
    }
  }
  kern[0*256 + t] = s0 * (1.0f/256.0f);
  kern[1*256 + t] = s1 * (1.0f/256.0f);
  kern[2*256 + t] = s2 * (1.0f/256.0f);
}

// Expand kernels into transposed dense operators Wg[band][q][p] = kern[band][rot(p,q)]
__global__ __launch_bounds__(256) void k_prep2(const float* __restrict__ kern,
                                               float* __restrict__ Wg){
  int band = blockIdx.x >> 8; int q = blockIdx.x & 255; int p = threadIdx.x;
  int p1 = p >> 4, p2 = p & 15, q1 = q >> 4, q2 = q & 15;
  Wg[(band << 16) + (q << 8) + p] =
      kern[(band << 8) + (((p1 - q1) & 15) << 4) + ((p2 - q2) & 15)];
}

// Transpose conv weights OIHW -> [ci*9+k][co] for coalesced per-lane reads
__global__ __launch_bounds__(320) void k_wt(const float* __restrict__ w,
                                            float* __restrict__ wt){
  int idx = blockIdx.x;           // ci*9 + k,  0..2879
  int co  = threadIdx.x;          // 0..319
  int ci = idx / 9, k = idx % 9;
  wt[idx * NC + co] = w[(co * NC + ci) * 9 + k];
}

// avg[b,c] = mean over 256 pixels. one wave per row.
__global__ __launch_bounds__(256) void k_avg(const float* __restrict__ x,
                                             float* __restrict__ avg){
  int w = threadIdx.x >> 6, l = threadIdx.x & 63;
  int row = blockIdx.x * 4 + w;
  const float* xr = x + (size_t)row * 256;
  float s = xr[l] + xr[l + 64] + xr[l + 128] + xr[l + 192];
  for (int o = 32; o > 0; o >>= 1) s += __shfl_down(s, o);
  if (l == 0) avg[row] = s * (1.0f/256.0f);
}

// channel-attention MLP per batch: cw[b][band*320+c]
__global__ __launch_bounds__(256) void k_ca(const float* __restrict__ avg,
                                            const float* __restrict__ w1,
                                            const float* __restrict__ b1,
                                            const float* __restrict__ w2,
                                            const float* __restrict__ b2,
                                            float* __restrict__ cw){
  __shared__ float a[NC];
  __shared__ float h[NHID];
  int b = blockIdx.x, t = threadIdx.x;
  a[t] = avg[b * NC + t];
  if (t < NC - 256) a[256 + t] = avg[b * NC + 256 + t];
  __syncthreads();
  if (t < NHID){
    float s = b1[t];
    for (int i = 0; i < NC; ++i) s += w1[t * NC + i] * a[i];
    h[t] = fmaxf(s, 0.0f);
  }
  __syncthreads();
  for (int o = t; o < 3 * NC; o += 256){
    float s = b2[o];
    for (int i = 0; i < NHID; ++i) s += w2[o * NHID + i] * h[i];
    cw[b * (3 * NC) + o] = sigf(s);
  }
}

// band filter: 8 rows of X per block, thread = pixel p.
// acc[r] += x[row_r][q] (wave-uniform -> scalar load) * Wg[q][p] (coalesced)
__global__ __launch_bounds__(256) void k_band(const float* __restrict__ x,
                                              const float* __restrict__ Wg,
                                              float* __restrict__ band){
  int p = threadIdx.x;
  const float* xb = x    + (size_t)blockIdx.x * (8 * 256);
  float*       ob = band + (size_t)blockIdx.x * (8 * 256);
  float a0=0,a1=0,a2=0,a3=0,a4=0,a5=0,a6=0,a7=0;
  #pragma unroll 4
  for (int q = 0; q < 256; ++q){
    float wv = Wg[(q << 8) + p];
    a0 += xb[q          ] * wv;  a1 += xb[256  + q] * wv;
    a2 += xb[512  + q   ] * wv;  a3 += xb[768  + q] * wv;
    a4 += xb[1024 + q   ] * wv;  a5 += xb[1280 + q] * wv;
    a6 += xb[1536 + q   ] * wv;  a7 += xb[1792 + q] * wv;
  }
  ob[p] = a0;            ob[256  + p] = a1;
  ob[512  + p] = a2;     ob[768  + p] = a3;
  ob[1024 + p] = a4;     ob[1280 + p] = a5;
  ob[1536 + p] = a6;     ob[1792 + p] = a7;
}

// conv3x3 SAME (zero pad), thread = output channel lane, block = (b, 2-row strip).
// Input rows are wave-uniform loads; weights coalesced via transposed wt.
__global__ __launch_bounds__(320) void k_conv(const float* __restrict__ band,
                                              const float* __restrict__ wt,
                                              const float* __restrict__ bias,
                                              float* __restrict__ out){
  int co = threadIdx.x;                 // 0..319
  int b  = blockIdx.x >> 3;
  int h0 = (blockIdx.x & 7) << 1;       // 0,2,..,14
  float acc[32];
  #pragma unroll
  for (int i = 0; i < 32; ++i) acc[i] = 0.f;
  const float* bb = band + ((size_t)b * NC << 8);
  for (int ci = 0; ci < NC; ++ci){
    const float* brow = bb + ((size_t)ci << 8);
    float rv[4][18];
    #pragma unroll
    for (int rr = 0; rr < 4; ++rr){
      int r = h0 - 1 + rr;
      rv[rr][0] = 0.f; rv[rr][17] = 0.f;
      if (r >= 0 && r < 16){
        #pragma unroll
        for (int j = 0; j < 16; ++j) rv[rr][1 + j] = brow[(r << 4) + j];
      } else {
        #pragma unroll
        for (int j = 0; j < 16; ++j) rv[rr][1 + j] = 0.f;
      }
    }
    const float* wrow = wt + (size_t)ci * 9 * NC + co;
    #pragma unroll
    for (int kh = 0; kh < 3; ++kh){
      #pragma unroll
      for (int kw = 0; kw < 3; ++kw){
        float wv = wrow[(kh * 3 + kw) * NC];
        #pragma unroll
        for (int orow = 0; orow < 2; ++orow){
          const float* rvp = rv[orow + kh];
          #pragma unroll
          for (int wc = 0; wc < 16; ++wc){
            acc[orow * 16 + wc] += wv * rvp[wc + kw];
          }
        }
      }
    }
  }
  float bi = bias[co];
  float* op = out + (((size_t)(b * NC + co)) << 8) + (h0 << 4);
  #pragma unroll
  for (int v = 0; v < 8; ++v){
    float4 t4 = { acc[v*4+0] + bi, acc[v*4+1] + bi, acc[v*4+2] + bi, acc[v*4+3] + bi };
    *(float4*)(op + v * 4) = t4;
  }
}

// GroupNorm statistics: one block per (b, group)
__global__ __launch_bounds__(256) void k_gnstats(const float* __restrict__ conv,
                                                 float* __restrict__ stats){
  int b = blockIdx.x / NG, g = blockIdx.x % NG;
  const float* p = conv + ((size_t)(b * NC + g * CPG)) * 256;
  float s = 0.f, s2 = 0.f;
  for (int i = threadIdx.x; i < CPG * 256; i += 256){
    float v = p[i]; s += v; s2 += v * v;
  }
  for (int o = 32; o > 0; o >>= 1){ s += __shfl_down(s, o); s2 += __shfl_down(s2, o); }
  __shared__ float rs[4], rs2[4];
  int w = threadIdx.x >> 6, l = threadIdx.x & 63;
  if (l == 0){ rs[w] = s; rs2[w] = s2; }
  __syncthreads();
  if (threadIdx.x == 0){
    float S = rs[0] + rs[1] + rs[2] + rs[3];
    float S2 = rs2[0] + rs2[1] + rs2[2] + rs2[3];
    float mu = S * (1.0f/16384.0f);
    float var = S2 * (1.0f/16384.0f) - mu * mu;
    stats[(b * NG + g) * 2 + 0] = mu;
    stats[(b * NG + g) * 2 + 1] = rsqrtf(var + 1e-5f);
  }
}

// apply GN + residual + channel weight, accumulate into fused (= d_out)
__global__ __launch_bounds__(256) void k_fuse(const float* __restrict__ conv,
                                              const float* __restrict__ x,
                                              const float* __restrict__ stats,
                                              const float* __restrict__ gamma,
                                              const float* __restrict__ beta,
                                              const float* __restrict__ cw,
                                              float* __restrict__ fused,
                                              int band){
  int i = blockIdx.x * 256 + threadIdx.x;        // < 10485760
  int row = i >> 8;
  int c = row % NC; int b = row / NC;
  int g = c / CPG;
  float mu = stats[(b * NG + g) * 2], rstd = stats[(b * NG + g) * 2 + 1];
  float v = (conv[i] - mu) * rstd * gamma[c] + beta[c] + x[i];
  float contrib = cw[b * (3 * NC) + band * NC + c] * v;
  if (band == 0) fused[i] = contrib; else fused[i] += contrib;
}

// spatial attention weights sw[b][p]
__global__ __launch_bounds__(256) void k_sa(const float* __restrict__ fused,
                                            const float* __restrict__ saw,
                                            const float* __restrict__ sab,
                                            float* __restrict__ sw){
  int b = blockIdx.x, p = threadIdx.x;
  const float* f = fused + (size_t)b * NC * 256 + p;
  float s = 0.f;
  for (int c = 0; c < NC; ++c) s += f[(size_t)c * 256] * saw[c];
  sw[b * 256 + p] = sigf(s + sab[0]);
}

__global__ __launch_bounds__(256) void k_scale(float* __restrict__ out,
                                               const float* __restrict__ sw){
  int i = blockIdx.x * 256 + threadIdx.x;
  int p = i & 255; int b = (i >> 8) / NC;
  out[i] = out[i] * sw[b * 256 + p];
}

extern "C" void kernel_launch(void* const* d_in, const int* in_sizes, int n_in,
                              void* d_out, int out_size, void* d_ws, size_t ws_size,
                              hipStream_t stream){
  const float* x     = (const float*)d_in[0];
  const float* lowc  = (const float*)d_in[1];
  const float* highc = (const float*)d_in[2];
  const float* ca_w1 = (const float*)d_in[3];
  const float* ca_b1 = (const float*)d_in[4];
  const float* ca_w2 = (const float*)d_in[5];
  const float* ca_b2 = (const float*)d_in[6];
  const float* conv_w[3] = {(const float*)d_in[7],  (const float*)d_in[11], (const float*)d_in[15]};
  const float* conv_b[3] = {(const float*)d_in[8],  (const float*)d_in[12], (const float*)d_in[16]};
  const float* gn_g[3]   = {(const float*)d_in[9],  (const float*)d_in[13], (const float*)d_in[17]};
  const float* gn_be[3]  = {(const float*)d_in[10], (const float*)d_in[14], (const float*)d_in[18]};
  const float* sa_w = (const float*)d_in[19];
  const float* sa_b = (const float*)d_in[20];
  float* out = (float*)d_out;

  float* ws    = (float*)d_ws;
  float* kern  = ws;                       // 768   (pad 1024)
  float* Wg    = ws + 1024;                // 196608
  float* WT    = Wg + 196608;              // 3*921600 = 2764800
  float* cw    = WT + 2764800;             // 122880
  float* avg   = cw + 122880;              // 40960
  float* stats = avg + 40960;              // 1280
  float* sw    = stats + 1280;             // 32768
  float* band_buf = ws + 3211264;          // 10485760
  float* conv_buf = band_buf + 10485760;   // 10485760  (total ~96.7 MB)

  k_prep <<<1,   256, 0, stream>>>(lowc, highc, kern);
  k_prep2<<<768, 256, 0, stream>>>(kern, Wg);
  for (int i = 0; i < 3; ++i)
    k_wt<<<2880, 320, 0, stream>>>(conv_w[i], WT + (size_t)i * 921600);

  k_avg<<<10240, 256, 0, stream>>>(x, avg);
  k_ca <<<NB,    256, 0, stream>>>(avg, ca_w1, ca_b1, ca_w2, ca_b2, cw);

  for (int i = 0; i < 3; ++i){
    k_band   <<<5120,  256, 0, stream>>>(x, Wg + (size_t)i * 65536, band_buf);
    k_conv   <<<1024,  320, 0, stream>>>(band_buf, WT + (size_t)i * 921600, conv_b[i], conv_buf);
    k_gnstats<<<NB*NG, 256, 0, stream>>>(conv_buf, stats);
    k_fuse   <<<40960, 256, 0, stream>>>(conv_buf, x, stats, gn_g[i], gn_be[i], cw, out, i);
  }

  k_sa   <<<NB,    256, 0, stream>>>(out, sa_w, sa_b, sw);
  k_scale<<<40960, 256, 0, stream>>>(out, sw);
}

// Round 2
// 924.489 us; speedup vs baseline: 3.3993x; 3.3993x over previous
//
#include <hip/hip_runtime.h>
#include <math.h>

#define NB 128
#define NC 320
#define NG 5
#define CPG 64
#define NHID 40

typedef short bf16x8 __attribute__((ext_vector_type(8)));
typedef short s16x4  __attribute__((ext_vector_type(4)));
typedef float f32x4  __attribute__((ext_vector_type(4)));

__device__ __forceinline__ float sigf(float x){ return 1.0f/(1.0f+expf(-x)); }

__device__ __forceinline__ unsigned short f2b(float f){
  unsigned u = __float_as_uint(f);
  unsigned r = (u + 0x7fffu + ((u >> 16) & 1u)) >> 16;
  return (unsigned short)r;
}

// ---------------------------------------------------------------------------
// Build 3 circular-conv kernels (16x16) implied by the frequency masks.
// ---------------------------------------------------------------------------
__global__ __launch_bounds__(256) void k_prep(const float* __restrict__ lowc,
                                              const float* __restrict__ highc,
                                              float* __restrict__ kern){
  int t = threadIdx.x;
  int d1 = t >> 4, d2 = t & 15;
  float lc = lowc[0], hc = highc[0];
  float s0 = 0.f, s1 = 0.f, s2 = 0.f;
  const float step = 2.0f / 15.0f;
  for (int a1 = 0; a1 < 16; ++a1){
    float cy = -1.0f + step * (float)a1;
    for (int a2 = 0; a2 < 16; ++a2){
      float cx = -1.0f + step * (float)a2;
      float dist = sqrtf(cx*cx + cy*cy) / 1.41421356237309515f;
      float lm = sigf((lc - dist) / 1e-6f);
      float hm = sigf((dist - hc) / 1e-6f);
      float mm = sigf((dist - lc) / 1e-6f) * sigf((hc - dist) / 1e-6f);
      int ang = ((a1 + 8) * d1 + (a2 + 8) * d2) & 15;
      float cv = cosf((float)ang * 0.392699081698724154f);
      s0 += lm * cv; s1 += mm * cv; s2 += hm * cv;
    }
  }
  kern[0*256 + t] = s0 * (1.0f/256.0f);
  kern[1*256 + t] = s1 * (1.0f/256.0f);
  kern[2*256 + t] = s2 * (1.0f/256.0f);
}

// WgT[band][p][q] = bf16(kern[band][rot(p-q)])  (B-operand: 8 contiguous q per lane)
__global__ __launch_bounds__(256) void k_prepWgT(const float* __restrict__ kern,
                                                 unsigned short* __restrict__ WgT){
  int band = blockIdx.x >> 8; int p = blockIdx.x & 255; int q = threadIdx.x;
  int p1 = p >> 4, p2 = p & 15, q1 = q >> 4, q2 = q & 15;
  float v = kern[(band << 8) + (((p1 - q1) & 15) << 4) + ((p2 - q2) & 15)];
  WgT[(size_t)(band << 16) + (p << 8) + q] = f2b(v);
}

// weights OIHW fp32 -> WA[tap][cib][cig][co][8j] bf16 (A-operand, coalesced)
__global__ __launch_bounds__(320) void k_wt2(const float* __restrict__ w,
                                             unsigned short* __restrict__ WAb){
  int blk = blockIdx.x;          // tap*40 + cib*4 + cig
  int co  = threadIdx.x;
  int tap = blk / 40; int rem = blk % 40; int cib = rem >> 2; int cig = rem & 3;
  unsigned short tmp[8];
  #pragma unroll
  for (int j = 0; j < 8; ++j){
    int ci = cib*32 + cig*8 + j;
    tmp[j] = f2b(w[((size_t)co * NC + ci) * 9 + tap]);
  }
  *(s16x4*)(WAb + ((size_t)blk * NC + co) * 8)     = *(s16x4*)tmp;
  *(s16x4*)(WAb + ((size_t)blk * NC + co) * 8 + 4) = *(s16x4*)(tmp + 4);
}

// x fp32 -> bf16
__global__ __launch_bounds__(256) void k_cast(const float* __restrict__ x,
                                              unsigned short* __restrict__ xb){
  int i = (blockIdx.x * 256 + threadIdx.x) * 4;
  float4 v = *(const float4*)(x + i);
  unsigned short o[4] = { f2b(v.x), f2b(v.y), f2b(v.z), f2b(v.w) };
  *(s16x4*)(xb + i) = *(s16x4*)o;
}

// avg[b,c]
__global__ __launch_bounds__(256) void k_avg(const float* __restrict__ x,
                                             float* __restrict__ avg){
  int w = threadIdx.x >> 6, l = threadIdx.x & 63;
  int row = blockIdx.x * 4 + w;
  const float* xr = x + (size_t)row * 256;
  float s = xr[l] + xr[l + 64] + xr[l + 128] + xr[l + 192];
  for (int o = 32; o > 0; o >>= 1) s += __shfl_down(s, o);
  if (l == 0) avg[row] = s * (1.0f/256.0f);
}

__global__ __launch_bounds__(256) void k_ca(const float* __restrict__ avg,
                                            const float* __restrict__ w1,
                                            const float* __restrict__ b1,
                                            const float* __restrict__ w2,
                                            const float* __restrict__ b2,
                                            float* __restrict__ cw){
  __shared__ float a[NC];
  __shared__ float h[NHID];
  int b = blockIdx.x, t = threadIdx.x;
  a[t] = avg[b * NC + t];
  if (t < NC - 256) a[256 + t] = avg[b * NC + 256 + t];
  __syncthreads();
  if (t < NHID){
    float s = b1[t];
    for (int i = 0; i < NC; ++i) s += w1[t * NC + i] * a[i];
    h[t] = fmaxf(s, 0.0f);
  }
  __syncthreads();
  for (int o = t; o < 3 * NC; o += 256){
    float s = b2[o];
    for (int i = 0; i < NHID; ++i) s += w2[o * NHID + i] * h[i];
    cw[b * (3 * NC) + o] = sigf(s);
  }
}

// ---------------------------------------------------------------------------
// Band GEMM: Band[row=b*320+ci][p] = xb[row][:] . WgT[p][:]   (K=256)
// writes bf16 into halo layout bandT[b][slot(h+1,w+1)][ci]
// ---------------------------------------------------------------------------
__global__ __launch_bounds__(256) void k_bandg(const unsigned short* __restrict__ xb,
                                               const unsigned short* __restrict__ WgT,
                                               unsigned short* __restrict__ bandT){
  int l  = threadIdx.x & 63;
  int wq = threadIdx.x >> 6;
  int cig = l >> 4, lan = l & 15;
  int b = blockIdx.x / 5;
  int cibase = (blockIdx.x % 5) * 64;
  size_t rowbase = (size_t)blockIdx.x * 64;

  f32x4 acc[4][4];
  #pragma unroll
  for (int m = 0; m < 4; ++m)
    #pragma unroll
    for (int n = 0; n < 4; ++n) acc[m][n] = (f32x4){0.f,0.f,0.f,0.f};

  #pragma unroll 2
  for (int ks = 0; ks < 8; ++ks){
    int koff = ks*32 + cig*8;
    bf16x8 a[4], bv[4];
    #pragma unroll
    for (int m = 0; m < 4; ++m)
      a[m] = *(const bf16x8*)(xb + (rowbase + m*16 + lan)*256 + koff);
    #pragma unroll
    for (int n = 0; n < 4; ++n){
      int p = wq*64 + n*16 + lan;
      bv[n] = *(const bf16x8*)(WgT + (size_t)p*256 + koff);
    }
    #pragma unroll
    for (int m = 0; m < 4; ++m)
      #pragma unroll
      for (int n = 0; n < 4; ++n)
        acc[m][n] = __builtin_amdgcn_mfma_f32_16x16x32_bf16(a[m], bv[n], acc[m][n], 0, 0, 0);
  }

  #pragma unroll
  for (int m = 0; m < 4; ++m){
    #pragma unroll
    for (int n = 0; n < 4; ++n){
      int p = wq*64 + n*16 + lan;
      int slot = ((p >> 4) + 1) * 18 + (p & 15) + 1;
      int ci = cibase + m*16 + cig*4;
      unsigned short o[4] = { f2b(acc[m][n][0]), f2b(acc[m][n][1]),
                              f2b(acc[m][n][2]), f2b(acc[m][n][3]) };
      *(s16x4*)(bandT + ((size_t)(b*324 + slot))*NC + ci) = *(s16x4*)o;
    }
  }
}

// ---------------------------------------------------------------------------
// Conv3x3 as 9-tap implicit GEMM. Out[b][co][p] = sum_tap,ci WA.Band(shifted)
// ---------------------------------------------------------------------------
__global__ __launch_bounds__(256) void k_convg(const unsigned short* __restrict__ bandT,
                                               const unsigned short* __restrict__ WAb,
                                               const float* __restrict__ bias,
                                               float* __restrict__ out){
  int l  = threadIdx.x & 63;
  int wq = threadIdx.x >> 6;
  int cig = l >> 4, lan = l & 15;
  int b = blockIdx.x / 5;
  int cobase = (blockIdx.x % 5) * 64;

  f32x4 acc[4][4];
  #pragma unroll
  for (int m = 0; m < 4; ++m)
    #pragma unroll
    for (int n = 0; n < 4; ++n) acc[m][n] = (f32x4){0.f,0.f,0.f,0.f};

  for (int tap = 0; tap < 9; ++tap){
    int dh = tap / 3 - 1, dw = tap % 3 - 1;
    const unsigned short* bp[4];
    #pragma unroll
    for (int n = 0; n < 4; ++n){
      int p = wq*64 + n*16 + lan;
      int slot = ((p >> 4) + dh + 1) * 18 + (p & 15) + dw + 1;
      bp[n] = bandT + ((size_t)(b*324 + slot))*NC + cig*8;
    }
    const unsigned short* ap = WAb + ((size_t)tap*40 + cig)*(NC*8) + (cobase + lan)*8;
    #pragma unroll 2
    for (int cib = 0; cib < 10; ++cib){
      bf16x8 a[4], bv[4];
      #pragma unroll
      for (int m = 0; m < 4; ++m)
        a[m] = *(const bf16x8*)(ap + m*128);
      #pragma unroll
      for (int n = 0; n < 4; ++n)
        bv[n] = *(const bf16x8*)(bp[n] + cib*32);
      #pragma unroll
      for (int m = 0; m < 4; ++m)
        #pragma unroll
        for (int n = 0; n < 4; ++n)
          acc[m][n] = __builtin_amdgcn_mfma_f32_16x16x32_bf16(a[m], bv[n], acc[m][n], 0, 0, 0);
      ap += 4 * NC * 8;
    }
  }

  #pragma unroll
  for (int m = 0; m < 4; ++m){
    #pragma unroll
    for (int r = 0; r < 4; ++r){
      int co = cobase + m*16 + cig*4 + r;
      float bi = bias[co];
      float* op = out + ((size_t)(b*NC + co))*256 + wq*64 + lan;
      #pragma unroll
      for (int n = 0; n < 4; ++n)
        op[n*16] = acc[m][n][r] + bi;
    }
  }
}

// GroupNorm statistics
__global__ __launch_bounds__(256) void k_gnstats(const float* __restrict__ conv,
                                                 float* __restrict__ stats){
  int b = blockIdx.x / NG, g = blockIdx.x % NG;
  const float* p = conv + ((size_t)(b * NC + g * CPG)) * 256;
  float s = 0.f, s2 = 0.f;
  for (int i = threadIdx.x; i < CPG * 256; i += 256){
    float v = p[i]; s += v; s2 += v * v;
  }
  for (int o = 32; o > 0; o >>= 1){ s += __shfl_down(s, o); s2 += __shfl_down(s2, o); }
  __shared__ float rs[4], rs2[4];
  int w = threadIdx.x >> 6, l = threadIdx.x & 63;
  if (l == 0){ rs[w] = s; rs2[w] = s2; }
  __syncthreads();
  if (threadIdx.x == 0){
    float S = rs[0] + rs[1] + rs[2] + rs[3];
    float S2 = rs2[0] + rs2[1] + rs2[2] + rs2[3];
    float mu = S * (1.0f/16384.0f);
    float var = S2 * (1.0f/16384.0f) - mu * mu;
    stats[(b * NG + g) * 2 + 0] = mu;
    stats[(b * NG + g) * 2 + 1] = rsqrtf(var + 1e-5f);
  }
}

__global__ __launch_bounds__(256) void k_fuse(const float* __restrict__ conv,
                                              const float* __restrict__ x,
                                              const float* __restrict__ stats,
                                              const float* __restrict__ gamma,
                                              const float* __restrict__ beta,
                                              const float* __restrict__ cw,
                                              float* __restrict__ fused,
                                              int band){
  int i = blockIdx.x * 256 + threadIdx.x;
  int row = i >> 8;
  int c = row % NC; int b = row / NC;
  int g = c / CPG;
  float mu = stats[(b * NG + g) * 2], rstd = stats[(b * NG + g) * 2 + 1];
  float v = (conv[i] - mu) * rstd * gamma[c] + beta[c] + x[i];
  float contrib = cw[b * (3 * NC) + band * NC + c] * v;
  if (band == 0) fused[i] = contrib; else fused[i] += contrib;
}

__global__ __launch_bounds__(256) void k_sa(const float* __restrict__ fused,
                                            const float* __restrict__ saw,
                                            const float* __restrict__ sab,
                                            float* __restrict__ sw){
  int b = blockIdx.x, p = threadIdx.x;
  const float* f = fused + (size_t)b * NC * 256 + p;
  float s = 0.f;
  for (int c = 0; c < NC; ++c) s += f[(size_t)c * 256] * saw[c];
  sw[b * 256 + p] = sigf(s + sab[0]);
}

__global__ __launch_bounds__(256) void k_scale(float* __restrict__ out,
                                               const float* __restrict__ sw){
  int i = blockIdx.x * 256 + threadIdx.x;
  int p = i & 255; int b = (i >> 8) / NC;
  out[i] = out[i] * sw[b * 256 + p];
}

extern "C" void kernel_launch(void* const* d_in, const int* in_sizes, int n_in,
                              void* d_out, int out_size, void* d_ws, size_t ws_size,
                              hipStream_t stream){
  const float* x     = (const float*)d_in[0];
  const float* lowc  = (const float*)d_in[1];
  const float* highc = (const float*)d_in[2];
  const float* ca_w1 = (const float*)d_in[3];
  const float* ca_b1 = (const float*)d_in[4];
  const float* ca_w2 = (const float*)d_in[5];
  const float* ca_b2 = (const float*)d_in[6];
  const float* conv_w[3] = {(const float*)d_in[7],  (const float*)d_in[11], (const float*)d_in[15]};
  const float* conv_b[3] = {(const float*)d_in[8],  (const float*)d_in[12], (const float*)d_in[16]};
  const float* gn_g[3]   = {(const float*)d_in[9],  (const float*)d_in[13], (const float*)d_in[17]};
  const float* gn_be[3]  = {(const float*)d_in[10], (const float*)d_in[14], (const float*)d_in[18]};
  const float* sa_w = (const float*)d_in[19];
  const float* sa_b = (const float*)d_in[20];
  float* out = (float*)d_out;

  // workspace layout (bytes from base):
  char* base = (char*)d_ws;
  float*          kern  = (float*)base;                        // 4096 B
  unsigned short* WgT   = (unsigned short*)(base + 4096);      // 3*65536*2   = 393216
  unsigned short* WAb   = (unsigned short*)(base + 397312);    // 3*921600*2  = 5529600
  unsigned short* xb    = (unsigned short*)(base + 5926912);   // 10485760*2  = 20971520
  unsigned short* bandT = (unsigned short*)(base + 26898432);  // 13271040*2  = 26542080
  float*          convb = (float*)(base + 53440512);           // 10485760*4  = 41943040
  float*          cw    = (float*)(base + 95383552);           // 122880*4
  float*          avg   = (float*)(base + 95875072);           // 40960*4
  float*          stats = (float*)(base + 96038912);           // 1280*4
  float*          sw    = (float*)(base + 96044032);           // 32768*4 -> end 96175104

  hipMemsetAsync(bandT, 0, 26542080, stream);   // zero halo (interior overwritten)

  k_prep   <<<1,   256, 0, stream>>>(lowc, highc, kern);
  k_prepWgT<<<768, 256, 0, stream>>>(kern, WgT);
  for (int i = 0; i < 3; ++i)
    k_wt2<<<360, 320, 0, stream>>>(conv_w[i], WAb + (size_t)i * 921600);
  k_cast<<<10240, 256, 0, stream>>>(x, xb);

  k_avg<<<10240, 256, 0, stream>>>(x, avg);
  k_ca <<<NB,    256, 0, stream>>>(avg, ca_w1, ca_b1, ca_w2, ca_b2, cw);

  for (int i = 0; i < 3; ++i){
    k_bandg  <<<640,   256, 0, stream>>>(xb, WgT + (size_t)i * 65536, bandT);
    k_convg  <<<640,   256, 0, stream>>>(bandT, WAb + (size_t)i * 921600, conv_b[i], convb);
    k_gnstats<<<NB*NG, 256, 0, stream>>>(convb, stats);
    k_fuse   <<<40960, 256, 0, stream>>>(convb, x, stats, gn_g[i], gn_be[i], cw, out, i);
  }

  k_sa   <<<NB,    256, 0, stream>>>(out, sa_w, sa_b, sw);
  k_scale<<<40960, 256, 0, stream>>>(out, sw);
}

// Round 3
// 803.256 us; speedup vs baseline: 3.9123x; 1.1509x over previous
//
#include <hip/hip_runtime.h>
#include <math.h>

#define NB 128
#define NC 320
#define NG 5
#define CPG 64
#define NHID 40

typedef short bf16x8 __attribute__((ext_vector_type(8)));
typedef short s16x4  __attribute__((ext_vector_type(4)));
typedef float f32x4  __attribute__((ext_vector_type(4)));

__device__ __forceinline__ float sigf(float x){ return 1.0f/(1.0f+expf(-x)); }

__device__ __forceinline__ unsigned short f2b(float f){
  unsigned u = __float_as_uint(f);
  unsigned r = (u + 0x7fffu + ((u >> 16) & 1u)) >> 16;
  return (unsigned short)r;
}
__device__ __forceinline__ float b2f(unsigned short u){
  return __uint_as_float(((unsigned)u) << 16);
}

__device__ __forceinline__ void gll16(const unsigned short* g, unsigned short* l){
  __builtin_amdgcn_global_load_lds(
      (const __attribute__((address_space(1))) void*)g,
      (__attribute__((address_space(3))) void*)l, 16, 0, 0);
}

// ---------------------------------------------------------------------------
// Build 3 circular-conv kernels (16x16) implied by the frequency masks.
// ---------------------------------------------------------------------------
__global__ __launch_bounds__(256) void k_prep(const float* __restrict__ lowc,
                                              const float* __restrict__ highc,
                                              float* __restrict__ kern){
  int t = threadIdx.x;
  int d1 = t >> 4, d2 = t & 15;
  float lc = lowc[0], hc = highc[0];
  float s0 = 0.f, s1 = 0.f, s2 = 0.f;
  const float step = 2.0f / 15.0f;
  for (int a1 = 0; a1 < 16; ++a1){
    float cy = -1.0f + step * (float)a1;
    for (int a2 = 0; a2 < 16; ++a2){
      float cx = -1.0f + step * (float)a2;
      float dist = sqrtf(cx*cx + cy*cy) / 1.41421356237309515f;
      float lm = sigf((lc - dist) / 1e-6f);
      float hm = sigf((dist - hc) / 1e-6f);
      float mm = sigf((dist - lc) / 1e-6f) * sigf((hc - dist) / 1e-6f);
      int ang = ((a1 + 8) * d1 + (a2 + 8) * d2) & 15;
      float cv = cosf((float)ang * 0.392699081698724154f);
      s0 += lm * cv; s1 += mm * cv; s2 += hm * cv;
    }
  }
  kern[0*256 + t] = s0 * (1.0f/256.0f);
  kern[1*256 + t] = s1 * (1.0f/256.0f);
  kern[2*256 + t] = s2 * (1.0f/256.0f);
}

// WgT[band][p][q] = bf16(kern[band][rot(p-q)])
__global__ __launch_bounds__(256) void k_prepWgT(const float* __restrict__ kern,
                                                 unsigned short* __restrict__ WgT){
  int band = blockIdx.x >> 8; int p = blockIdx.x & 255; int q = threadIdx.x;
  int p1 = p >> 4, p2 = p & 15, q1 = q >> 4, q2 = q & 15;
  float v = kern[(band << 8) + (((p1 - q1) & 15) << 4) + ((p2 - q2) & 15)];
  WgT[(size_t)(band << 16) + (p << 8) + q] = f2b(v);
}

// weights OIHW fp32 -> WA[tap][cib][cig][co][8j] bf16
__global__ __launch_bounds__(320) void k_wt2(const float* __restrict__ w,
                                             unsigned short* __restrict__ WAb){
  int blk = blockIdx.x;          // tap*40 + cib*4 + cig
  int co  = threadIdx.x;
  int tap = blk / 40; int rem = blk % 40; int cib = rem >> 2; int cig = rem & 3;
  unsigned short tmp[8];
  #pragma unroll
  for (int j = 0; j < 8; ++j){
    int ci = cib*32 + cig*8 + j;
    tmp[j] = f2b(w[((size_t)co * NC + ci) * 9 + tap]);
  }
  *(s16x4*)(WAb + ((size_t)blk * NC + co) * 8)     = *(s16x4*)tmp;
  *(s16x4*)(WAb + ((size_t)blk * NC + co) * 8 + 4) = *(s16x4*)(tmp + 4);
}

// avg[b,c]
__global__ __launch_bounds__(256) void k_avg(const float* __restrict__ x,
                                             float* __restrict__ avg){
  int w = threadIdx.x >> 6, l = threadIdx.x & 63;
  int row = blockIdx.x * 4 + w;
  const float* xr = x + (size_t)row * 256;
  float s = xr[l] + xr[l + 64] + xr[l + 128] + xr[l + 192];
  for (int o = 32; o > 0; o >>= 1) s += __shfl_down(s, o);
  if (l == 0) avg[row] = s * (1.0f/256.0f);
}

__global__ __launch_bounds__(256) void k_ca(const float* __restrict__ avg,
                                            const float* __restrict__ w1,
                                            const float* __restrict__ b1,
                                            const float* __restrict__ w2,
                                            const float* __restrict__ b2,
                                            float* __restrict__ cw){
  __shared__ float a[NC];
  __shared__ float h[NHID];
  int b = blockIdx.x, t = threadIdx.x;
  a[t] = avg[b * NC + t];
  if (t < NC - 256) a[256 + t] = avg[b * NC + 256 + t];
  __syncthreads();
  if (t < NHID){
    float s = b1[t];
    for (int i = 0; i < NC; ++i) s += w1[t * NC + i] * a[i];
    h[t] = fmaxf(s, 0.0f);
  }
  __syncthreads();
  for (int o = t; o < 3 * NC; o += 256){
    float s = b2[o];
    for (int i = 0; i < NHID; ++i) s += w2[o * NHID + i] * h[i];
    cw[b * (3 * NC) + o] = sigf(s);
  }
}

// ---------------------------------------------------------------------------
// Band GEMM: Band[row=b*320+ci][p] = x[row][:] . WgT[p][:]   (K=256)
// reads x fp32, writes bf16 into halo layout bandT[b][slot(h+1,w+1)][ci]
// ---------------------------------------------------------------------------
__global__ __launch_bounds__(256) void k_bandg(const float* __restrict__ x,
                                               const unsigned short* __restrict__ WgT,
                                               unsigned short* __restrict__ bandT){
  int l  = threadIdx.x & 63;
  int wq = threadIdx.x >> 6;
  int cig = l >> 4, lan = l & 15;
  int b = blockIdx.x / 5;
  int cibase = (blockIdx.x % 5) * 64;
  size_t rowbase = (size_t)blockIdx.x * 64;

  f32x4 acc[4][4];
  #pragma unroll
  for (int m = 0; m < 4; ++m)
    #pragma unroll
    for (int n = 0; n < 4; ++n) acc[m][n] = (f32x4){0.f,0.f,0.f,0.f};

  #pragma unroll 2
  for (int ks = 0; ks < 8; ++ks){
    int koff = ks*32 + cig*8;
    bf16x8 a[4], bv[4];
    #pragma unroll
    for (int m = 0; m < 4; ++m){
      const float* xp = x + (rowbase + m*16 + lan)*256 + koff;
      float4 f0 = *(const float4*)xp;
      float4 f1 = *(const float4*)(xp + 4);
      unsigned short t[8] = { f2b(f0.x), f2b(f0.y), f2b(f0.z), f2b(f0.w),
                              f2b(f1.x), f2b(f1.y), f2b(f1.z), f2b(f1.w) };
      a[m] = *(bf16x8*)t;
    }
    #pragma unroll
    for (int n = 0; n < 4; ++n){
      int p = wq*64 + n*16 + lan;
      bv[n] = *(const bf16x8*)(WgT + (size_t)p*256 + koff);
    }
    #pragma unroll
    for (int m = 0; m < 4; ++m)
      #pragma unroll
      for (int n = 0; n < 4; ++n)
        acc[m][n] = __builtin_amdgcn_mfma_f32_16x16x32_bf16(a[m], bv[n], acc[m][n], 0, 0, 0);
  }

  #pragma unroll
  for (int m = 0; m < 4; ++m){
    #pragma unroll
    for (int n = 0; n < 4; ++n){
      int p = wq*64 + n*16 + lan;
      int slot = ((p >> 4) + 1) * 18 + (p & 15) + 1;
      int ci = cibase + m*16 + cig*4;
      unsigned short o[4] = { f2b(acc[m][n][0]), f2b(acc[m][n][1]),
                              f2b(acc[m][n][2]), f2b(acc[m][n][3]) };
      *(s16x4*)(bandT + ((size_t)(b*324 + slot))*NC + ci) = *(s16x4*)o;
    }
  }
}

// ---------------------------------------------------------------------------
// Conv3x3 implicit GEMM, M=320 x N=128 per block, A staged via global_load_lds,
// double-buffered; GN partial stats computed in-kernel (deterministic).
// grid 256 = (batch, pixel-half), XCD-swizzled. 8 waves (4m x 2n).
// ---------------------------------------------------------------------------
__global__ __launch_bounds__(512) void k_convg(const unsigned short* __restrict__ bandT,
                                               const unsigned short* __restrict__ WAb,
                                               const float* __restrict__ bias,
                                               unsigned short* __restrict__ convb,
                                               float* __restrict__ stats_part,
                                               int band){
  __shared__ unsigned short lds[2*10240];   // 2 x 20KB A chunks
  __shared__ float stw[8][5][2];

  int tid = threadIdx.x;
  int orig = (blockIdx.x & 7)*32 + (blockIdx.x >> 3);   // XCD-bijective swizzle
  int b = orig >> 1, half = orig & 1;
  int l = tid & 63, w = tid >> 6;
  int wr = w >> 1, wn = w & 1;             // 4 m-groups x 2 n-groups
  int cig = l >> 4, lan = l & 15;
  int p0 = half*128 + wn*64;

  int sbase[4];
  #pragma unroll
  for (int n = 0; n < 4; ++n){
    int p = p0 + n*16 + lan;
    sbase[n] = b*324 + ((p >> 4) + 1)*18 + (p & 15) + 1;
  }

  f32x4 acc[5][4];
  #pragma unroll
  for (int m = 0; m < 5; ++m)
    #pragma unroll
    for (int n = 0; n < 4; ++n) acc[m][n] = (f32x4){0.f,0.f,0.f,0.f};

  // stage chunk kk into buffer bufi (20480 bytes = 10240 shorts)
  auto stage = [&](int kk, int bufi){
    int tap = kk % 9, cib = kk / 9;
    const unsigned short* src = WAb + ((size_t)(tap*40 + cib*4))*2560;
    unsigned short* dst = lds + bufi*10240;
    gll16(src + tid*8,        dst + w*512);
    gll16(src + 4096 + tid*8, dst + 4096 + w*512);
    if (tid < 256) gll16(src + 8192 + tid*8, dst + 8192 + w*512);
  };

  stage(0, 0);
  __syncthreads();

  for (int kk = 0; kk < 90; ++kk){
    int bufi = kk & 1;
    if (kk < 89) stage(kk + 1, bufi ^ 1);

    int tap = kk % 9, cib = kk / 9;
    int dh = tap/3 - 1, dw = tap%3 - 1;

    bf16x8 bv[4];
    #pragma unroll
    for (int n = 0; n < 4; ++n)
      bv[n] = *(const bf16x8*)(bandT + (size_t)(sbase[n] + dh*18 + dw)*NC + cib*32 + cig*8);

    const unsigned short* A = lds + bufi*10240;
    bf16x8 a[5];
    #pragma unroll
    for (int m = 0; m < 5; ++m)
      a[m] = *(const bf16x8*)(A + ((size_t)(cig*320 + wr*80 + m*16 + lan))*8);

    #pragma unroll
    for (int m = 0; m < 5; ++m)
      #pragma unroll
      for (int n = 0; n < 4; ++n)
        acc[m][n] = __builtin_amdgcn_mfma_f32_16x16x32_bf16(a[m], bv[n], acc[m][n], 0, 0, 0);

    __syncthreads();
  }

  // fold bias (GN stats must include it)
  #pragma unroll
  for (int m = 0; m < 5; ++m)
    #pragma unroll
    for (int r = 0; r < 4; ++r){
      float bvs = bias[wr*80 + m*16 + cig*4 + r];
      #pragma unroll
      for (int n = 0; n < 4; ++n) acc[m][n][r] += bvs;
    }

  // per-wave GN partial sums (deterministic: per-(wave,m) slots, no atomics)
  #pragma unroll
  for (int m = 0; m < 5; ++m){
    float s = 0.f, q = 0.f;
    #pragma unroll
    for (int n = 0; n < 4; ++n)
      #pragma unroll
      for (int r = 0; r < 4; ++r){ float v = acc[m][n][r]; s += v; q += v*v; }
    #pragma unroll
    for (int o = 32; o > 0; o >>= 1){ s += __shfl_xor(s, o); q += __shfl_xor(q, o); }
    if (l == 0){ stw[w][m][0] = s; stw[w][m][1] = q; }
  }

  // store bf16 conv output
  #pragma unroll
  for (int m = 0; m < 5; ++m)
    #pragma unroll
    for (int r = 0; r < 4; ++r){
      int co = wr*80 + m*16 + cig*4 + r;
      unsigned short* op = convb + ((size_t)(b*NC + co))*256 + p0 + lan;
      #pragma unroll
      for (int n = 0; n < 4; ++n) op[n*16] = f2b(acc[m][n][r]);
    }

  __syncthreads();
  if (tid < 10){
    int g = tid >> 1, wh = tid & 1;
    float t = 0.f;
    for (int w2 = 0; w2 < 8; ++w2)
      #pragma unroll
      for (int m = 0; m < 5; ++m)
        if ((((w2 >> 1)*80 + m*16) >> 6) == g) t += stw[w2][m][wh];
    stats_part[((size_t)(band*NB + b)*NG + g)*4 + half*2 + wh] = t;
  }
}

// ---------------------------------------------------------------------------
// Fused epilogue: GN finalize + residual + channel-weights + SA + scale.
// One block per batch, 512 threads (2 ci-lanes x 256 pixels).
// ---------------------------------------------------------------------------
__global__ __launch_bounds__(512) void k_fuse3(const unsigned short* __restrict__ cb0,
                                               const unsigned short* __restrict__ cb1,
                                               const unsigned short* __restrict__ cb2,
                                               const float* __restrict__ x,
                                               const float* __restrict__ stats_part,
                                               const float* __restrict__ g0, const float* __restrict__ be0,
                                               const float* __restrict__ g1, const float* __restrict__ be1,
                                               const float* __restrict__ g2, const float* __restrict__ be2,
                                               const float* __restrict__ cw,
                                               const float* __restrict__ saw,
                                               const float* __restrict__ sab,
                                               float* __restrict__ out){
  __shared__ float mu_s[3][NG], rs_s[3][NG], sh[2][256];
  int b = blockIdx.x;
  int tid = threadIdx.x;
  if (tid < 15){
    int band = tid / 5, g = tid % 5;
    const float* sp = stats_part + ((size_t)(band*NB + b)*NG + g)*4;
    float s = sp[0] + sp[2], q = sp[1] + sp[3];
    float mu = s * (1.f/16384.f);
    float var = q * (1.f/16384.f) - mu*mu;
    mu_s[band][g] = mu; rs_s[band][g] = rsqrtf(var + 1e-5f);
  }
  __syncthreads();

  int p = tid & 255, cs = tid >> 8;
  float sacc = 0.f;
  const float* cwb = cw + b*960;
  for (int ci = cs; ci < NC; ci += 2){
    int g = ci >> 6;
    size_t idx = ((size_t)(b*NC + ci))*256 + p;
    float xv = x[idx];
    float f =
      cwb[ci      ] * ((b2f(cb0[idx]) - mu_s[0][g])*rs_s[0][g]*g0[ci] + be0[ci] + xv) +
      cwb[320 + ci] * ((b2f(cb1[idx]) - mu_s[1][g])*rs_s[1][g]*g1[ci] + be1[ci] + xv) +
      cwb[640 + ci] * ((b2f(cb2[idx]) - mu_s[2][g])*rs_s[2][g]*g2[ci] + be2[ci] + xv);
    out[idx] = f;
    sacc += f * saw[ci];
  }
  sh[cs][p] = sacc;
  __syncthreads();
  if (tid < 256) sh[0][tid] = sigf(sh[0][tid] + sh[1][tid] + sab[0]);
  __syncthreads();
  float swv = sh[0][p];
  for (int ci = cs; ci < NC; ci += 2){
    size_t idx = ((size_t)(b*NC + ci))*256 + p;
    out[idx] *= swv;
  }
}

extern "C" void kernel_launch(void* const* d_in, const int* in_sizes, int n_in,
                              void* d_out, int out_size, void* d_ws, size_t ws_size,
                              hipStream_t stream){
  const float* x     = (const float*)d_in[0];
  const float* lowc  = (const float*)d_in[1];
  const float* highc = (const float*)d_in[2];
  const float* ca_w1 = (const float*)d_in[3];
  const float* ca_b1 = (const float*)d_in[4];
  const float* ca_w2 = (const float*)d_in[5];
  const float* ca_b2 = (const float*)d_in[6];
  const float* conv_w[3] = {(const float*)d_in[7],  (const float*)d_in[11], (const float*)d_in[15]};
  const float* conv_b[3] = {(const float*)d_in[8],  (const float*)d_in[12], (const float*)d_in[16]};
  const float* gn_g[3]   = {(const float*)d_in[9],  (const float*)d_in[13], (const float*)d_in[17]};
  const float* gn_be[3]  = {(const float*)d_in[10], (const float*)d_in[14], (const float*)d_in[18]};
  const float* sa_w = (const float*)d_in[19];
  const float* sa_b = (const float*)d_in[20];
  float* out = (float*)d_out;

  char* base = (char*)d_ws;
  float*          kern  = (float*)base;                        // 4 KB
  unsigned short* WgT   = (unsigned short*)(base + 4096);      // 393216
  unsigned short* WAb   = (unsigned short*)(base + 397312);    // 5529600
  unsigned short* bandT = (unsigned short*)(base + 5926912);   // 26542080
  unsigned short* cb[3] = {(unsigned short*)(base + 32468992),
                           (unsigned short*)(base + 53440512),
                           (unsigned short*)(base + 74412032)}; // 3 x 20971520
  float*          cw    = (float*)(base + 95383552);           // 491520
  float*          avg   = (float*)(base + 95875072);           // 163840
  float*          stats = (float*)(base + 96038912);           // 30720

  hipMemsetAsync(bandT, 0, 26542080, stream);   // zero halo once

  k_prep   <<<1,   256, 0, stream>>>(lowc, highc, kern);
  k_prepWgT<<<768, 256, 0, stream>>>(kern, WgT);
  for (int i = 0; i < 3; ++i)
    k_wt2<<<360, 320, 0, stream>>>(conv_w[i], WAb + (size_t)i * 921600);

  k_avg<<<10240, 256, 0, stream>>>(x, avg);
  k_ca <<<NB,    256, 0, stream>>>(avg, ca_w1, ca_b1, ca_w2, ca_b2, cw);

  for (int i = 0; i < 3; ++i){
    k_bandg<<<640, 256, 0, stream>>>(x, WgT + (size_t)i * 65536, bandT);
    k_convg<<<256, 512, 0, stream>>>(bandT, WAb + (size_t)i * 921600, conv_b[i],
                                     cb[i], stats, i);
  }

  k_fuse3<<<NB, 512, 0, stream>>>(cb[0], cb[1], cb[2], x, stats,
                                  gn_g[0], gn_be[0], gn_g[1], gn_be[1], gn_g[2], gn_be[2],
                                  cw, sa_w, sa_b, out);
}

// Round 4
// 679.447 us; speedup vs baseline: 4.6252x; 1.1822x over previous
//
#include <hip/hip_runtime.h>
#include <math.h>

#define NB 128
#define NC 320
#define NG 5
#define CPG 64
#define NHID 40

typedef short bf16x8 __attribute__((ext_vector_type(8)));
typedef short s16x4  __attribute__((ext_vector_type(4)));
typedef float f32x4  __attribute__((ext_vector_type(4)));

__device__ __forceinline__ float sigf(float x){ return 1.0f/(1.0f+expf(-x)); }

__device__ __forceinline__ unsigned short f2b(float f){
  unsigned u = __float_as_uint(f);
  unsigned r = (u + 0x7fffu + ((u >> 16) & 1u)) >> 16;
  return (unsigned short)r;
}
__device__ __forceinline__ float b2f(unsigned short u){
  return __uint_as_float(((unsigned)u) << 16);
}

__device__ __forceinline__ void gll16(const unsigned short* g, unsigned short* l){
  __builtin_amdgcn_global_load_lds(
      (const __attribute__((address_space(1))) void*)g,
      (__attribute__((address_space(3))) void*)l, 16, 0, 0);
}

// masks[band][s] for the 3 frequency masks (replicates JAX fp32 arithmetic)
__global__ __launch_bounds__(256) void k_mask(const float* __restrict__ lowc,
                                              const float* __restrict__ highc,
                                              float* __restrict__ mask){
  int t = threadIdx.x;
  int a1 = t >> 4, a2 = t & 15;
  float lc = lowc[0], hc = highc[0];
  const float step = 2.0f / 15.0f;
  float cy = -1.0f + step * (float)a1;
  float cx = -1.0f + step * (float)a2;
  float dist = sqrtf(cx*cx + cy*cy) / 1.41421356237309515f;
  mask[t]       = sigf((lc - dist) * 1e6f);
  mask[256 + t] = sigf((dist - lc) * 1e6f) * sigf((hc - dist) * 1e6f);
  mask[512 + t] = sigf((dist - hc) * 1e6f);
}

// WgT[band][p][q] = bf16( (1/256) sum_s mask[band][s] cos(2pi((s1+8)d1+(s2+8)d2)/16) ),
// d = (p - q) mod 16 componentwise.
__global__ __launch_bounds__(256) void k_prepWgT(const float* __restrict__ mask,
                                                 unsigned short* __restrict__ WgT){
  __shared__ float cost[16];
  __shared__ float msh[256];
  int band = blockIdx.x >> 8, p = blockIdx.x & 255;
  int q = threadIdx.x;
  if (q < 16) cost[q] = cosf((float)q * 0.392699081698724154f);
  msh[q] = mask[band*256 + q];
  __syncthreads();
  int d1 = ((p >> 4) - (q >> 4)) & 15;
  int d2 = ((p & 15) - (q & 15)) & 15;
  float s = 0.f;
  int ang0 = (8*d1 + 8*d2) & 15;
  for (int a1 = 0; a1 < 16; ++a1){
    int ang = (ang0 + a1*d1) & 15;
    #pragma unroll
    for (int a2 = 0; a2 < 16; ++a2){
      s += msh[a1*16 + a2] * cost[ang];
      ang = (ang + d2) & 15;
    }
  }
  WgT[(size_t)(band << 16) + (p << 8) + q] = f2b(s * (1.0f/256.0f));
}

// weights OIHW fp32 -> WA[band][tap][cib][cig][co][8j] bf16
__global__ __launch_bounds__(320) void k_wt2(const float* __restrict__ w0,
                                             const float* __restrict__ w1,
                                             const float* __restrict__ w2,
                                             unsigned short* __restrict__ WAb){
  int band = blockIdx.x / 360, blk = blockIdx.x % 360;
  const float* w = band == 0 ? w0 : (band == 1 ? w1 : w2);
  int co  = threadIdx.x;
  int tap = blk / 40; int rem = blk % 40; int cib = rem >> 2; int cig = rem & 3;
  unsigned short tmp[8];
  #pragma unroll
  for (int j = 0; j < 8; ++j){
    int ci = cib*32 + cig*8 + j;
    tmp[j] = f2b(w[((size_t)co * NC + ci) * 9 + tap]);
  }
  unsigned short* dst = WAb + (size_t)band*921600 + ((size_t)blk * NC + co) * 8;
  *(s16x4*)dst       = *(s16x4*)tmp;
  *(s16x4*)(dst + 4) = *(s16x4*)(tmp + 4);
}

// zero the 68 halo slots of each (band,b) tile
__global__ __launch_bounds__(256) void k_zerohalo(unsigned short* __restrict__ bandT){
  unsigned short* base = bandT + (size_t)blockIdx.x * 103680;   // 324*320
  for (int i = threadIdx.x; i < 5440; i += 256){
    int idx = i / 80, v = i % 80;
    int r, c;
    if (idx < 18)      { r = 0;        c = idx;      }
    else if (idx < 36) { r = 17;       c = idx - 18; }
    else if (idx < 52) { r = idx - 35; c = 0;        }
    else               { r = idx - 51; c = 17;       }
    s16x4 z = {0,0,0,0};
    *(s16x4*)(base + (size_t)(r*18 + c)*NC + v*4) = z;
  }
}

__global__ __launch_bounds__(256) void k_ca(const float* __restrict__ avg,
                                            const float* __restrict__ w1,
                                            const float* __restrict__ b1,
                                            const float* __restrict__ w2,
                                            const float* __restrict__ b2,
                                            float* __restrict__ cw){
  __shared__ float a[NC];
  __shared__ float h[NHID];
  int b = blockIdx.x, t = threadIdx.x;
  a[t] = avg[b * NC + t];
  if (t < NC - 256) a[256 + t] = avg[b * NC + 256 + t];
  __syncthreads();
  if (t < NHID){
    float s = b1[t];
    for (int i = 0; i < NC; ++i) s += w1[t * NC + i] * a[i];
    h[t] = fmaxf(s, 0.0f);
  }
  __syncthreads();
  for (int o = t; o < 3 * NC; o += 256){
    float s = b2[o];
    for (int i = 0; i < NHID; ++i) s += w2[o * NHID + i] * h[i];
    cw[b * (3 * NC) + o] = sigf(s);
  }
}

// ---------------------------------------------------------------------------
// Band GEMM (all 3 bands in one grid when bandSel<0): X staged once into
// XOR-swizzled bf16 LDS; also emits avg[b][c] as a staging byproduct.
// ---------------------------------------------------------------------------
__global__ __launch_bounds__(256, 4) void k_bandg(const float* __restrict__ x,
                                                  const unsigned short* __restrict__ WgT,
                                                  unsigned short* __restrict__ bandT,
                                                  float* __restrict__ avgOut,
                                                  int bandSel, int chunk, int strideBand){
  __shared__ unsigned short xt[64*256];   // 32 KB, col16-granule XOR-swizzled
  int tid = threadIdx.x;
  int wgid = (blockIdx.x & 7)*chunk + (blockIdx.x >> 3);
  int band, rem;
  if (bandSel >= 0){ band = bandSel; rem = wgid; }
  else { band = wgid / 640; rem = wgid - band*640; }
  int b = rem / 5, cq = rem - b*5;
  const unsigned short* Wg = WgT + (size_t)band * 65536;
  unsigned short* bT = bandT + (strideBand ? (size_t)band * 13271040 : (size_t)0);
  int cibase = cq * 64;
  size_t rowbase = (size_t)(b*5 + cq) * 64;

  // stage 64 rows x 256 cols of x -> bf16 LDS (swizzled), fold row-mean
  {
    int r = tid >> 2, c0 = (tid & 3) * 64;
    const float* xp = x + (rowbase + r)*256 + c0;
    unsigned short* dp = xt + r*256;
    int sw = (r & 7) << 3;
    float rs = 0.f;
    #pragma unroll
    for (int j = 0; j < 64; j += 4){
      float4 f = *(const float4*)(xp + j);
      rs += f.x + f.y + f.z + f.w;
      unsigned short t4[4] = { f2b(f.x), f2b(f.y), f2b(f.z), f2b(f.w) };
      *(s16x4*)(dp + ((c0 + j) ^ sw)) = *(s16x4*)t4;
    }
    rs += __shfl_down(rs, 1);
    rs += __shfl_down(rs, 2);
    if ((tid & 3) == 0) avgOut[rowbase + r] = rs * (1.0f/256.0f);
  }
  __syncthreads();

  int l  = tid & 63;
  int wq = tid >> 6;
  int cig = l >> 4, lan = l & 15;

  f32x4 acc[4][4];
  #pragma unroll
  for (int m = 0; m < 4; ++m)
    #pragma unroll
    for (int n = 0; n < 4; ++n) acc[m][n] = (f32x4){0.f,0.f,0.f,0.f};

  #pragma unroll 2
  for (int ks = 0; ks < 8; ++ks){
    int koff = ks*32 + cig*8;
    bf16x8 a[4], bv[4];
    #pragma unroll
    for (int m = 0; m < 4; ++m){
      int row = m*16 + lan;
      a[m] = *(const bf16x8*)(xt + row*256 + (koff ^ ((row & 7) << 3)));
    }
    #pragma unroll
    for (int n = 0; n < 4; ++n){
      int p = wq*64 + n*16 + lan;
      bv[n] = *(const bf16x8*)(Wg + (size_t)p*256 + koff);
    }
    #pragma unroll
    for (int m = 0; m < 4; ++m)
      #pragma unroll
      for (int n = 0; n < 4; ++n)
        acc[m][n] = __builtin_amdgcn_mfma_f32_16x16x32_bf16(a[m], bv[n], acc[m][n], 0, 0, 0);
  }

  #pragma unroll
  for (int m = 0; m < 4; ++m){
    #pragma unroll
    for (int n = 0; n < 4; ++n){
      int p = wq*64 + n*16 + lan;
      int slot = ((p >> 4) + 1) * 18 + (p & 15) + 1;
      int ci = cibase + m*16 + cig*4;
      unsigned short o[4] = { f2b(acc[m][n][0]), f2b(acc[m][n][1]),
                              f2b(acc[m][n][2]), f2b(acc[m][n][3]) };
      *(s16x4*)(bT + ((size_t)(b*324 + slot))*NC + ci) = *(s16x4*)o;
    }
  }
}

// ---------------------------------------------------------------------------
// Conv3x3 implicit GEMM, all 3 bands in one grid when bandSel<0.
// Block = (band, b, 64-px quarter): M=320 x N=64, 8 waves (4 co-groups x 2 px).
// A (weights) staged via global_load_lds, double-buffered; GN partials fused.
// ---------------------------------------------------------------------------
__global__ __launch_bounds__(512, 5) void k_convg(const unsigned short* __restrict__ bandT,
                                                  const unsigned short* __restrict__ WAb,
                                                  const float* __restrict__ bias0,
                                                  const float* __restrict__ bias1,
                                                  const float* __restrict__ bias2,
                                                  unsigned short* __restrict__ convb,
                                                  float* __restrict__ stats_part,
                                                  int bandSel, int chunk, int strideBand){
  __shared__ unsigned short lds[2*10240];   // 2 x 20KB A chunks
  __shared__ float stw[8][5][2];

  int tid = threadIdx.x;
  int wgid = (blockIdx.x & 7)*chunk + (blockIdx.x >> 3);
  int band, rem;
  if (bandSel >= 0){ band = bandSel; rem = wgid; }
  else { band = wgid >> 9; rem = wgid & 511; }
  int b = rem >> 2, quarter = rem & 3;

  const unsigned short* bT = bandT + (strideBand ? (size_t)band * 13271040 : (size_t)0);
  const unsigned short* WA = WAb + (size_t)band * 921600;
  const float* bias = band == 0 ? bias0 : (band == 1 ? bias1 : bias2);
  unsigned short* cb = convb + (size_t)band * 10485760;

  int l = tid & 63, w = tid >> 6;
  int wr = w >> 1, wn = w & 1;            // 4 co-groups x 2 px-halves(32px)
  int cig = l >> 4, lan = l & 15;
  int p0 = quarter*64 + wn*32;

  int sbase[2];
  #pragma unroll
  for (int n = 0; n < 2; ++n){
    int p = p0 + n*16 + lan;
    sbase[n] = b*324 + ((p >> 4) + 1)*18 + (p & 15) + 1;
  }

  f32x4 acc[5][2];
  #pragma unroll
  for (int m = 0; m < 5; ++m)
    #pragma unroll
    for (int n = 0; n < 2; ++n) acc[m][n] = (f32x4){0.f,0.f,0.f,0.f};

  auto stage = [&](int tap, int cib, int bufi){
    const unsigned short* src = WA + ((size_t)(tap*40 + cib*4))*2560;
    unsigned short* dst = lds + bufi*10240;
    gll16(src + tid*8,        dst + w*512);
    gll16(src + 4096 + tid*8, dst + 4096 + w*512);
    if (tid < 256) gll16(src + 8192 + tid*8, dst + 8192 + w*512);
  };

  stage(0, 0, 0);
  __syncthreads();

  int kk = 0;
  for (int cib = 0; cib < 10; ++cib){
    int cioff = cib*32 + cig*8;
    for (int tap = 0; tap < 9; ++tap, ++kk){
      int bufi = kk & 1;
      int dh = tap/3 - 1, dw = tap%3 - 1;

      bf16x8 bv[2];
      #pragma unroll
      for (int n = 0; n < 2; ++n)
        bv[n] = *(const bf16x8*)(bT + (size_t)(sbase[n] + dh*18 + dw)*NC + cioff);

      if (kk < 89){
        int nt = tap + 1, ncb = cib;
        if (nt == 9){ nt = 0; ++ncb; }
        stage(nt, ncb, bufi ^ 1);
      }

      const unsigned short* A = lds + bufi*10240;
      bf16x8 a[5];
      #pragma unroll
      for (int m = 0; m < 5; ++m)
        a[m] = *(const bf16x8*)(A + ((size_t)(cig*320 + wr*80 + m*16 + lan))*8);

      __builtin_amdgcn_s_setprio(1);
      #pragma unroll
      for (int m = 0; m < 5; ++m)
        #pragma unroll
        for (int n = 0; n < 2; ++n)
          acc[m][n] = __builtin_amdgcn_mfma_f32_16x16x32_bf16(a[m], bv[n], acc[m][n], 0, 0, 0);
      __builtin_amdgcn_s_setprio(0);

      __syncthreads();
    }
  }

  // fold bias (GN stats must include it)
  #pragma unroll
  for (int m = 0; m < 5; ++m)
    #pragma unroll
    for (int r = 0; r < 4; ++r){
      float bvs = bias[wr*80 + m*16 + cig*4 + r];
      #pragma unroll
      for (int n = 0; n < 2; ++n) acc[m][n][r] += bvs;
    }

  // per-wave GN partial sums (deterministic)
  #pragma unroll
  for (int m = 0; m < 5; ++m){
    float s = 0.f, q = 0.f;
    #pragma unroll
    for (int n = 0; n < 2; ++n)
      #pragma unroll
      for (int r = 0; r < 4; ++r){ float v = acc[m][n][r]; s += v; q += v*v; }
    #pragma unroll
    for (int o = 32; o > 0; o >>= 1){ s += __shfl_xor(s, o); q += __shfl_xor(q, o); }
    if (l == 0){ stw[w][m][0] = s; stw[w][m][1] = q; }
  }

  // store bf16 conv output
  #pragma unroll
  for (int m = 0; m < 5; ++m)
    #pragma unroll
    for (int r = 0; r < 4; ++r){
      int co = wr*80 + m*16 + cig*4 + r;
      unsigned short* op = cb + ((size_t)(b*NC + co))*256 + p0 + lan;
      #pragma unroll
      for (int n = 0; n < 2; ++n) op[n*16] = f2b(acc[m][n][r]);
    }

  __syncthreads();
  if (tid < 10){
    int g = tid >> 1, wh = tid & 1;
    float t = 0.f;
    for (int w2 = 0; w2 < 8; ++w2)
      #pragma unroll
      for (int m = 0; m < 5; ++m)
        if ((((w2 >> 1)*80 + m*16) >> 6) == g) t += stw[w2][m][wh];
    stats_part[((size_t)(band*NB + b)*NG + g)*8 + quarter*2 + wh] = t;
  }
}

// ---------------------------------------------------------------------------
// Fused epilogue: GN finalize + residual + channel-weights + SA + scale.
// ---------------------------------------------------------------------------
__global__ __launch_bounds__(1024) void k_fuse3(const unsigned short* __restrict__ cb0,
                                                const unsigned short* __restrict__ cb1,
                                                const unsigned short* __restrict__ cb2,
                                                const float* __restrict__ x,
                                                const float* __restrict__ stats_part,
                                                const float* __restrict__ g0, const float* __restrict__ be0,
                                                const float* __restrict__ g1, const float* __restrict__ be1,
                                                const float* __restrict__ g2, const float* __restrict__ be2,
                                                const float* __restrict__ cw,
                                                const float* __restrict__ saw,
                                                const float* __restrict__ sab,
                                                float* __restrict__ out){
  __shared__ float mu_s[3][NG], rs_s[3][NG], sh[4][256];
  int b = blockIdx.x;
  int tid = threadIdx.x;
  if (tid < 15){
    int band = tid / 5, g = tid % 5;
    const float* sp = stats_part + ((size_t)(band*NB + b)*NG + g)*8;
    float s = sp[0] + sp[2] + sp[4] + sp[6];
    float q = sp[1] + sp[3] + sp[5] + sp[7];
    float mu = s * (1.f/16384.f);
    float var = q * (1.f/16384.f) - mu*mu;
    mu_s[band][g] = mu; rs_s[band][g] = rsqrtf(var + 1e-5f);
  }
  __syncthreads();

  int p = tid & 255, cs = tid >> 8;
  float sacc = 0.f;
  const float* cwb = cw + b*960;
  for (int ci = cs; ci < NC; ci += 4){
    int g = ci >> 6;
    size_t idx = ((size_t)(b*NC + ci))*256 + p;
    float xv = x[idx];
    float f =
      cwb[ci      ] * ((b2f(cb0[idx]) - mu_s[0][g])*rs_s[0][g]*g0[ci] + be0[ci] + xv) +
      cwb[320 + ci] * ((b2f(cb1[idx]) - mu_s[1][g])*rs_s[1][g]*g1[ci] + be1[ci] + xv) +
      cwb[640 + ci] * ((b2f(cb2[idx]) - mu_s[2][g])*rs_s[2][g]*g2[ci] + be2[ci] + xv);
    out[idx] = f;
    sacc += f * saw[ci];
  }
  sh[cs][p] = sacc;
  __syncthreads();
  if (tid < 256) sh[0][tid] = sigf(sh[0][tid] + sh[1][tid] + sh[2][tid] + sh[3][tid] + sab[0]);
  __syncthreads();
  float swv = sh[0][p];
  for (int ci = cs; ci < NC; ci += 4){
    size_t idx = ((size_t)(b*NC + ci))*256 + p;
    out[idx] *= swv;
  }
}

extern "C" void kernel_launch(void* const* d_in, const int* in_sizes, int n_in,
                              void* d_out, int out_size, void* d_ws, size_t ws_size,
                              hipStream_t stream){
  (void)in_sizes; (void)n_in; (void)out_size;
  const float* x     = (const float*)d_in[0];
  const float* lowc  = (const float*)d_in[1];
  const float* highc = (const float*)d_in[2];
  const float* ca_w1 = (const float*)d_in[3];
  const float* ca_b1 = (const float*)d_in[4];
  const float* ca_w2 = (const float*)d_in[5];
  const float* ca_b2 = (const float*)d_in[6];
  const float* conv_w[3] = {(const float*)d_in[7],  (const float*)d_in[11], (const float*)d_in[15]};
  const float* conv_b[3] = {(const float*)d_in[8],  (const float*)d_in[12], (const float*)d_in[16]};
  const float* gn_g[3]   = {(const float*)d_in[9],  (const float*)d_in[13], (const float*)d_in[17]};
  const float* gn_be[3]  = {(const float*)d_in[10], (const float*)d_in[14], (const float*)d_in[18]};
  const float* sa_w = (const float*)d_in[19];
  const float* sa_b = (const float*)d_in[20];
  float* out = (float*)d_out;

  char* base = (char*)d_ws;
  float*          mask = (float*)base;                         // 3072 B (pad 4096)
  unsigned short* WgT  = (unsigned short*)(base + 4096);       // 393216
  unsigned short* WAb  = (unsigned short*)(base + 397312);     // 5529600 -> 5926912

  const size_t FUSED_BYTES = 149184512;
  bool fused = ws_size >= FUSED_BYTES;

  unsigned short *bandT, *cbb;
  float *cw, *avg, *stats;
  if (fused){
    bandT = (unsigned short*)(base + 5926912);     // 3 x 26542080 = 79626240
    cbb   = (unsigned short*)(base + 85553152);    // 3 x 20971520 = 62914560
    cw    = (float*)(base + 148467712);            // 491520
    avg   = (float*)(base + 148959232);            // 163840
    stats = (float*)(base + 149123072);            // 61440 -> 149184512
  } else {
    bandT = (unsigned short*)(base + 5926912);     // 26542080
    cbb   = (unsigned short*)(base + 32468992);    // 62914560
    cw    = (float*)(base + 95383552);             // 491520
    avg   = (float*)(base + 95875072);             // 163840
    stats = (float*)(base + 96038912);             // 61440 -> 96100352
  }
  unsigned short* cb0 = cbb;
  unsigned short* cb1 = cbb + 10485760;
  unsigned short* cb2 = cbb + 20971520;

  k_mask   <<<1,    256, 0, stream>>>(lowc, highc, mask);
  k_prepWgT<<<768,  256, 0, stream>>>(mask, WgT);
  k_wt2    <<<1080, 320, 0, stream>>>(conv_w[0], conv_w[1], conv_w[2], WAb);

  if (fused){
    k_zerohalo<<<384,  256, 0, stream>>>(bandT);
    k_bandg   <<<1920, 256, 0, stream>>>(x, WgT, bandT, avg, -1, 240, 1);
    k_ca      <<<NB,   256, 0, stream>>>(avg, ca_w1, ca_b1, ca_w2, ca_b2, cw);
    k_convg   <<<1536, 512, 0, stream>>>(bandT, WAb, conv_b[0], conv_b[1], conv_b[2],
                                         cbb, stats, -1, 192, 1);
  } else {
    k_zerohalo<<<128, 256, 0, stream>>>(bandT);
    for (int i = 0; i < 3; ++i){
      k_bandg<<<640, 256, 0, stream>>>(x, WgT, bandT, avg, i, 80, 0);
      k_convg<<<512, 512, 0, stream>>>(bandT, WAb, conv_b[0], conv_b[1], conv_b[2],
                                       cbb, stats, i, 64, 0);
    }
    k_ca<<<NB, 256, 0, stream>>>(avg, ca_w1, ca_b1, ca_w2, ca_b2, cw);
  }

  k_fuse3<<<NB, 1024, 0, stream>>>(cb0, cb1, cb2, x, stats,
                                   gn_g[0], gn_be[0], gn_g[1], gn_be[1], gn_g[2], gn_be[2],
                                   cw, sa_w, sa_b, out);
}

// Round 5
// 617.047 us; speedup vs baseline: 5.0930x; 1.1011x over previous
//
#include <hip/hip_runtime.h>
#include <math.h>

#define NB 128
#define NC 320
#define NG 5
#define CPG 64
#define NHID 40

typedef short bf16x8 __attribute__((ext_vector_type(8)));
typedef short s16x4  __attribute__((ext_vector_type(4)));
typedef float f32x4  __attribute__((ext_vector_type(4)));

__device__ __forceinline__ float sigf(float x){ return 1.0f/(1.0f+expf(-x)); }

__device__ __forceinline__ unsigned short f2b(float f){
  unsigned u = __float_as_uint(f);
  unsigned r = (u + 0x7fffu + ((u >> 16) & 1u)) >> 16;
  return (unsigned short)r;
}
__device__ __forceinline__ float b2f(unsigned short u){
  return __uint_as_float(((unsigned)u) << 16);
}

__device__ __forceinline__ void gll16(const unsigned short* g, unsigned short* l){
  __builtin_amdgcn_global_load_lds(
      (const __attribute__((address_space(1))) void*)g,
      (__attribute__((address_space(3))) void*)l, 16, 0, 0);
}

// masks[band][s] for the 3 frequency masks (replicates JAX fp32 arithmetic)
__global__ __launch_bounds__(256) void k_mask(const float* __restrict__ lowc,
                                              const float* __restrict__ highc,
                                              float* __restrict__ mask){
  int t = threadIdx.x;
  int a1 = t >> 4, a2 = t & 15;
  float lc = lowc[0], hc = highc[0];
  const float step = 2.0f / 15.0f;
  float cy = -1.0f + step * (float)a1;
  float cx = -1.0f + step * (float)a2;
  float dist = sqrtf(cx*cx + cy*cy) / 1.41421356237309515f;
  mask[t]       = sigf((lc - dist) * 1e6f);
  mask[256 + t] = sigf((dist - lc) * 1e6f) * sigf((hc - dist) * 1e6f);
  mask[512 + t] = sigf((dist - hc) * 1e6f);
}

// WgT[band][p][q] = bf16( (1/256) sum_s mask[band][s] cos(2pi dot((s+8),(p-q))/16) )
__global__ __launch_bounds__(256) void k_prepWgT(const float* __restrict__ mask,
                                                 unsigned short* __restrict__ WgT){
  __shared__ float cost[16];
  __shared__ float msh[256];
  int band = blockIdx.x >> 8, p = blockIdx.x & 255;
  int q = threadIdx.x;
  if (q < 16) cost[q] = cosf((float)q * 0.392699081698724154f);
  msh[q] = mask[band*256 + q];
  __syncthreads();
  int d1 = ((p >> 4) - (q >> 4)) & 15;
  int d2 = ((p & 15) - (q & 15)) & 15;
  float s = 0.f;
  int ang0 = (8*d1 + 8*d2) & 15;
  for (int a1 = 0; a1 < 16; ++a1){
    int ang = (ang0 + a1*d1) & 15;
    #pragma unroll
    for (int a2 = 0; a2 < 16; ++a2){
      s += msh[a1*16 + a2] * cost[ang];
      ang = (ang + d2) & 15;
    }
  }
  WgT[(size_t)(band << 16) + (p << 8) + q] = f2b(s * (1.0f/256.0f));
}

// weights OIHW fp32 -> WA[band][tap][cib][cig][co][8j] bf16
__global__ __launch_bounds__(320) void k_wt2(const float* __restrict__ w0,
                                             const float* __restrict__ w1,
                                             const float* __restrict__ w2,
                                             unsigned short* __restrict__ WAb){
  int band = blockIdx.x / 360, blk = blockIdx.x % 360;
  const float* w = band == 0 ? w0 : (band == 1 ? w1 : w2);
  int co  = threadIdx.x;
  int tap = blk / 40; int rem = blk % 40; int cib = rem >> 2; int cig = rem & 3;
  unsigned short tmp[8];
  #pragma unroll
  for (int j = 0; j < 8; ++j){
    int ci = cib*32 + cig*8 + j;
    tmp[j] = f2b(w[((size_t)co * NC + ci) * 9 + tap]);
  }
  unsigned short* dst = WAb + (size_t)band*921600 + ((size_t)blk * NC + co) * 8;
  *(s16x4*)dst       = *(s16x4*)tmp;
  *(s16x4*)(dst + 4) = *(s16x4*)(tmp + 4);
}

// zero the 68 halo slots of each (band,b) tile
__global__ __launch_bounds__(256) void k_zerohalo(unsigned short* __restrict__ bandT){
  unsigned short* base = bandT + (size_t)blockIdx.x * 103680;   // 324*320
  for (int i = threadIdx.x; i < 5440; i += 256){
    int idx = i / 80, v = i % 80;
    int r, c;
    if (idx < 18)      { r = 0;        c = idx;      }
    else if (idx < 36) { r = 17;       c = idx - 18; }
    else if (idx < 52) { r = idx - 35; c = 0;        }
    else               { r = idx - 51; c = 17;       }
    s16x4 z = {0,0,0,0};
    *(s16x4*)(base + (size_t)(r*18 + c)*NC + v*4) = z;
  }
}

__global__ __launch_bounds__(256) void k_ca(const float* __restrict__ avg,
                                            const float* __restrict__ w1,
                                            const float* __restrict__ b1,
                                            const float* __restrict__ w2,
                                            const float* __restrict__ b2,
                                            float* __restrict__ cw){
  __shared__ float a[NC];
  __shared__ float h[NHID];
  int b = blockIdx.x, t = threadIdx.x;
  a[t] = avg[b * NC + t];
  if (t < NC - 256) a[256 + t] = avg[b * NC + 256 + t];
  __syncthreads();
  if (t < NHID){
    float s = b1[t];
    for (int i = 0; i < NC; ++i) s += w1[t * NC + i] * a[i];
    h[t] = fmaxf(s, 0.0f);
  }
  __syncthreads();
  for (int o = t; o < 3 * NC; o += 256){
    float s = b2[o];
    for (int i = 0; i < NHID; ++i) s += w2[o * NHID + i] * h[i];
    cw[b * (3 * NC) + o] = sigf(s);
  }
}

// ---------------------------------------------------------------------------
// Band GEMM, ALL 3 BANDS per block: X (64 ci rows x 256 px) staged once into
// XOR-swizzled bf16 LDS; emits avg[b][c] as staging byproduct.
// grid 640 = (b, ci-quarter), XCD-chunked.
// ---------------------------------------------------------------------------
__global__ __launch_bounds__(256, 4) void k_bandg3(const float* __restrict__ x,
                                                   const unsigned short* __restrict__ WgT,
                                                   unsigned short* __restrict__ bandT,
                                                   float* __restrict__ avgOut){
  __shared__ unsigned short xt[64*256];   // 32 KB
  int tid = threadIdx.x;
  int wgid = (blockIdx.x & 7)*80 + (blockIdx.x >> 3);
  int b = wgid / 5, cq = wgid % 5;
  int cibase = cq * 64;
  size_t rowbase = (size_t)wgid * 64;

  // stage 64 rows x 256 cols of x -> bf16 LDS (swizzled), fold row-mean
  {
    int r = tid >> 2, c0 = (tid & 3) * 64;
    const float* xp = x + (rowbase + r)*256 + c0;
    unsigned short* dp = xt + r*256;
    int sw = (r & 7) << 3;
    float rs = 0.f;
    #pragma unroll
    for (int j = 0; j < 64; j += 4){
      float4 f = *(const float4*)(xp + j);
      rs += f.x + f.y + f.z + f.w;
      unsigned short t4[4] = { f2b(f.x), f2b(f.y), f2b(f.z), f2b(f.w) };
      *(s16x4*)(dp + ((c0 + j) ^ sw)) = *(s16x4*)t4;
    }
    rs += __shfl_down(rs, 1);
    rs += __shfl_down(rs, 2);
    if ((tid & 3) == 0) avgOut[rowbase + r] = rs * (1.0f/256.0f);
  }
  __syncthreads();

  int l  = tid & 63;
  int wq = tid >> 6;
  int cig = l >> 4, lan = l & 15;

  for (int band = 0; band < 3; ++band){
    const unsigned short* Wg = WgT + (size_t)band * 65536;
    unsigned short* bT = bandT + (size_t)band * 13271040;

    f32x4 acc[4][4];
    #pragma unroll
    for (int m = 0; m < 4; ++m)
      #pragma unroll
      for (int n = 0; n < 4; ++n) acc[m][n] = (f32x4){0.f,0.f,0.f,0.f};

    #pragma unroll 2
    for (int ks = 0; ks < 8; ++ks){
      int koff = ks*32 + cig*8;
      bf16x8 a[4], bv[4];
      #pragma unroll
      for (int m = 0; m < 4; ++m){
        int row = m*16 + lan;
        a[m] = *(const bf16x8*)(xt + row*256 + (koff ^ ((row & 7) << 3)));
      }
      #pragma unroll
      for (int n = 0; n < 4; ++n){
        int p = wq*64 + n*16 + lan;
        bv[n] = *(const bf16x8*)(Wg + (size_t)p*256 + koff);
      }
      #pragma unroll
      for (int m = 0; m < 4; ++m)
        #pragma unroll
        for (int n = 0; n < 4; ++n)
          acc[m][n] = __builtin_amdgcn_mfma_f32_16x16x32_bf16(a[m], bv[n], acc[m][n], 0, 0, 0);
    }

    #pragma unroll
    for (int m = 0; m < 4; ++m){
      #pragma unroll
      for (int n = 0; n < 4; ++n){
        int p = wq*64 + n*16 + lan;
        int slot = ((p >> 4) + 1) * 18 + (p & 15) + 1;
        int ci = cibase + m*16 + cig*4;
        unsigned short o[4] = { f2b(acc[m][n][0]), f2b(acc[m][n][1]),
                                f2b(acc[m][n][2]), f2b(acc[m][n][3]) };
        *(s16x4*)(bT + ((size_t)(b*324 + slot))*NC + ci) = *(s16x4*)o;
      }
    }
  }
}

// ---------------------------------------------------------------------------
// Conv3x3 implicit GEMM: one block = one (band, batch). M=320 x N=256, K=2880.
// 8 waves (4 co-groups x 2 px-halves); wave tile 80co x 128px (acc 5x8).
// Weights staged 20KB/K-step via global_load_lds, double-buffered.
// Full GN stats finalized in-kernel.
// ---------------------------------------------------------------------------
__global__ __launch_bounds__(512, 2) void k_convg(const unsigned short* __restrict__ bandT,
                                                  const unsigned short* __restrict__ WAb,
                                                  const float* __restrict__ bias0,
                                                  const float* __restrict__ bias1,
                                                  const float* __restrict__ bias2,
                                                  unsigned short* __restrict__ convb,
                                                  float* __restrict__ stats){
  __shared__ unsigned short lds[2*10240];   // 2 x 20KB A chunks
  __shared__ float stw[8][5][2];

  int tid = threadIdx.x;
  int wgid = (blockIdx.x & 7)*48 + (blockIdx.x >> 3);   // band-major XCD chunks
  int band = wgid >> 7, b = wgid & 127;

  const unsigned short* bT = bandT + (size_t)band * 13271040;
  const unsigned short* WA = WAb + (size_t)band * 921600;
  const float* bias = band == 0 ? bias0 : (band == 1 ? bias1 : bias2);
  unsigned short* cb = convb + (size_t)band * 10485760;

  int l = tid & 63, w = tid >> 6;
  int wr = w >> 1, wn = w & 1;            // 4 co-groups x 2 px-halves
  int cig = l >> 4, lan = l & 15;
  int p0 = wn*128;

  int sb[8];
  #pragma unroll
  for (int n = 0; n < 8; ++n)
    sb[n] = b*324 + (wn*8 + n + 1)*18 + lan + 1;

  f32x4 acc[5][8];
  #pragma unroll
  for (int m = 0; m < 5; ++m)
    #pragma unroll
    for (int n = 0; n < 8; ++n) acc[m][n] = (f32x4){0.f,0.f,0.f,0.f};

  auto stage = [&](int tap, int cib, int bufi){
    const unsigned short* src = WA + ((size_t)(tap*40 + cib*4))*2560;
    unsigned short* dst = lds + bufi*10240;
    gll16(src + tid*8,        dst + w*512);
    gll16(src + 4096 + tid*8, dst + 4096 + w*512);
    if (tid < 256) gll16(src + 8192 + tid*8, dst + 8192 + w*512);
  };

  stage(0, 0, 0);
  __syncthreads();

  int kk = 0;
  for (int cib = 0; cib < 10; ++cib){
    int cioff = cib*32 + cig*8;
    for (int tap = 0; tap < 9; ++tap, ++kk){
      int bufi = kk & 1;
      int dh = tap/3 - 1, dw = tap%3 - 1;

      bf16x8 bv[8];
      #pragma unroll
      for (int n = 0; n < 8; ++n)
        bv[n] = *(const bf16x8*)(bT + (size_t)(sb[n] + dh*18 + dw)*NC + cioff);

      if (kk < 89){
        int nt = tap + 1, ncb = cib;
        if (nt == 9){ nt = 0; ++ncb; }
        stage(nt, ncb, bufi ^ 1);
      }

      const unsigned short* A = lds + bufi*10240;
      bf16x8 a[5];
      #pragma unroll
      for (int m = 0; m < 5; ++m)
        a[m] = *(const bf16x8*)(A + ((size_t)(cig*320 + wr*80 + m*16 + lan))*8);

      __builtin_amdgcn_s_setprio(1);
      #pragma unroll
      for (int m = 0; m < 5; ++m)
        #pragma unroll
        for (int n = 0; n < 8; ++n)
          acc[m][n] = __builtin_amdgcn_mfma_f32_16x16x32_bf16(a[m], bv[n], acc[m][n], 0, 0, 0);
      __builtin_amdgcn_s_setprio(0);

      __syncthreads();
    }
  }

  // fold bias (GN stats must include it)
  #pragma unroll
  for (int m = 0; m < 5; ++m)
    #pragma unroll
    for (int r = 0; r < 4; ++r){
      float bvs = bias[wr*80 + m*16 + cig*4 + r];
      #pragma unroll
      for (int n = 0; n < 8; ++n) acc[m][n][r] += bvs;
    }

  // per-wave GN partial sums
  #pragma unroll
  for (int m = 0; m < 5; ++m){
    float s = 0.f, q = 0.f;
    #pragma unroll
    for (int n = 0; n < 8; ++n)
      #pragma unroll
      for (int r = 0; r < 4; ++r){ float v = acc[m][n][r]; s += v; q += v*v; }
    #pragma unroll
    for (int o = 32; o > 0; o >>= 1){ s += __shfl_xor(s, o); q += __shfl_xor(q, o); }
    if (l == 0){ stw[w][m][0] = s; stw[w][m][1] = q; }
  }

  // store bf16 conv output
  #pragma unroll
  for (int m = 0; m < 5; ++m)
    #pragma unroll
    for (int r = 0; r < 4; ++r){
      int co = wr*80 + m*16 + cig*4 + r;
      unsigned short* op = cb + ((size_t)(b*NC + co))*256 + p0 + lan;
      #pragma unroll
      for (int n = 0; n < 8; ++n) op[n*16] = f2b(acc[m][n][r]);
    }

  __syncthreads();
  if (tid < NG){
    int g = tid;
    float s = 0.f, q = 0.f;
    for (int w2 = 0; w2 < 8; ++w2)
      #pragma unroll
      for (int m = 0; m < 5; ++m)
        if ((((w2 >> 1)*80 + m*16) >> 6) == g){ s += stw[w2][m][0]; q += stw[w2][m][1]; }
    float mu = s * (1.f/16384.f);
    float var = q * (1.f/16384.f) - mu*mu;
    stats[((size_t)(band*NB + b)*NG + g)*2    ] = mu;
    stats[((size_t)(band*NB + b)*NG + g)*2 + 1] = rsqrtf(var + 1e-5f);
  }
}

// ---------------------------------------------------------------------------
// Fused epilogue (single pass): GN + residual + channel-weights + SA + scale.
// Block = (b, 128-px half); f kept in LDS (bf16), out written once.
// ---------------------------------------------------------------------------
__global__ __launch_bounds__(512) void k_fuse3(const unsigned short* __restrict__ cb0,
                                               const unsigned short* __restrict__ cb1,
                                               const unsigned short* __restrict__ cb2,
                                               const float* __restrict__ x,
                                               const float* __restrict__ stats,
                                               const float* __restrict__ g0, const float* __restrict__ be0,
                                               const float* __restrict__ g1, const float* __restrict__ be1,
                                               const float* __restrict__ g2, const float* __restrict__ be2,
                                               const float* __restrict__ cw,
                                               const float* __restrict__ saw,
                                               const float* __restrict__ sab,
                                               float* __restrict__ out){
  __shared__ unsigned short fl[NC*128];     // 80 KB
  __shared__ float mu_s[3][NG], rs_s[3][NG], sh[4][128];
  int b = blockIdx.x >> 1, half = blockIdx.x & 1;
  int tid = threadIdx.x;
  if (tid < 15){
    int band = tid / 5, g = tid % 5;
    const float* sp = stats + ((size_t)(band*NB + b)*NG + g)*2;
    mu_s[band][g] = sp[0]; rs_s[band][g] = sp[1];
  }
  __syncthreads();

  int p = tid & 127, cs = tid >> 7;
  int px = half*128 + p;
  float sacc = 0.f;
  const float* cwb = cw + b*960;
  for (int ci = cs; ci < NC; ci += 4){
    int g = ci >> 6;
    size_t idx = ((size_t)(b*NC + ci))*256 + px;
    float xv = x[idx];
    float f =
      cwb[ci      ] * ((b2f(cb0[idx]) - mu_s[0][g])*rs_s[0][g]*g0[ci] + be0[ci] + xv) +
      cwb[320 + ci] * ((b2f(cb1[idx]) - mu_s[1][g])*rs_s[1][g]*g1[ci] + be1[ci] + xv) +
      cwb[640 + ci] * ((b2f(cb2[idx]) - mu_s[2][g])*rs_s[2][g]*g2[ci] + be2[ci] + xv);
    fl[ci*128 + p] = f2b(f);
    sacc += f * saw[ci];
  }
  sh[cs][p] = sacc;
  __syncthreads();
  if (tid < 128) sh[0][tid] = sigf(sh[0][tid] + sh[1][tid] + sh[2][tid] + sh[3][tid] + sab[0]);
  __syncthreads();
  float swv = sh[0][p];
  for (int ci = cs; ci < NC; ci += 4){
    size_t idx = ((size_t)(b*NC + ci))*256 + px;
    out[idx] = b2f(fl[ci*128 + p]) * swv;
  }
}

extern "C" void kernel_launch(void* const* d_in, const int* in_sizes, int n_in,
                              void* d_out, int out_size, void* d_ws, size_t ws_size,
                              hipStream_t stream){
  (void)in_sizes; (void)n_in; (void)out_size; (void)ws_size;
  const float* x     = (const float*)d_in[0];
  const float* lowc  = (const float*)d_in[1];
  const float* highc = (const float*)d_in[2];
  const float* ca_w1 = (const float*)d_in[3];
  const float* ca_b1 = (const float*)d_in[4];
  const float* ca_w2 = (const float*)d_in[5];
  const float* ca_b2 = (const float*)d_in[6];
  const float* conv_w[3] = {(const float*)d_in[7],  (const float*)d_in[11], (const float*)d_in[15]};
  const float* conv_b[3] = {(const float*)d_in[8],  (const float*)d_in[12], (const float*)d_in[16]};
  const float* gn_g[3]   = {(const float*)d_in[9],  (const float*)d_in[13], (const float*)d_in[17]};
  const float* gn_be[3]  = {(const float*)d_in[10], (const float*)d_in[14], (const float*)d_in[18]};
  const float* sa_w = (const float*)d_in[19];
  const float* sa_b = (const float*)d_in[20];
  float* out = (float*)d_out;

  char* base = (char*)d_ws;
  float*          mask  = (float*)base;                        // 4 KB
  unsigned short* WgT   = (unsigned short*)(base + 4096);      // 393216
  unsigned short* WAb   = (unsigned short*)(base + 397312);    // 5529600 -> 5926912
  unsigned short* bandT = (unsigned short*)(base + 5926912);   // 3 x 26542080 = 79626240
  unsigned short* cbb   = (unsigned short*)(base + 85553152);  // 3 x 20971520 = 62914560
  float*          cw    = (float*)(base + 148467712);          // 491520
  float*          avg   = (float*)(base + 148959232);          // 163840
  float*          stats = (float*)(base + 149123072);          // 15360 -> 149138432
  unsigned short* cb0 = cbb;
  unsigned short* cb1 = cbb + 10485760;
  unsigned short* cb2 = cbb + 20971520;

  k_mask    <<<1,    256, 0, stream>>>(lowc, highc, mask);
  k_prepWgT <<<768,  256, 0, stream>>>(mask, WgT);
  k_wt2     <<<1080, 320, 0, stream>>>(conv_w[0], conv_w[1], conv_w[2], WAb);
  k_zerohalo<<<384,  256, 0, stream>>>(bandT);

  k_bandg3<<<640, 256, 0, stream>>>(x, WgT, bandT, avg);
  k_ca    <<<NB,  256, 0, stream>>>(avg, ca_w1, ca_b1, ca_w2, ca_b2, cw);

  k_convg<<<384, 512, 0, stream>>>(bandT, WAb, conv_b[0], conv_b[1], conv_b[2],
                                   cbb, stats);

  k_fuse3<<<256, 512, 0, stream>>>(cb0, cb1, cb2, x, stats,
                                   gn_g[0], gn_be[0], gn_g[1], gn_be[1], gn_g[2], gn_be[2],
                                   cw, sa_w, sa_b, out);
}